// Round 10
// baseline (210.491 us; speedup 1.0000x reference)
//
#include <hip/hip_runtime.h>
#include <stdint.h>

// RelationalNetwork: B=8, C=64, O=256, TE=128, GT=FP=256, A=32
// v10 structure (3 launches):
//   k_pre : W2/W3 transpose->bf16, summed:=0, U/V precompute (pipelined)
//   k_fuse: tile = 128 pairs (257*128 = 32896 exact), 512 thr / 8 waves,
//           LDS = 64KiB h1/h2 tile only -> 2 blocks/CU (4 waves/SIMD).
//           h1 built once into LDS; GEMM1 N-split swapped mfma(W2,h1)
//           with W2^T slices from L2 (2-deep prefetch), b64 h2^T scatter;
//           GEMM2 N-split with W3^T slices from L2; colsum -> atomicAdd.
//   k_tail: f_phi on 8 blocks x 1024 threads (4-way k-split per layer)

#define NPAIR 32896
#define NTILE 257    // 128 pairs per tile, exact

using short8  = __attribute__((ext_vector_type(8))) short;
using float4v = __attribute__((ext_vector_type(4))) float;

__device__ __forceinline__ float asf(unsigned u) {
    union { unsigned u; float f; } c; c.u = u; return c.f;
}
__device__ __forceinline__ unsigned short f2bf(float f) {
    union { float f; unsigned u; } c; c.f = f;
    unsigned u = c.u;
    u += 0x7FFFu + ((u >> 16) & 1u);   // RNE
    return (unsigned short)(u >> 16);
}
// packed f32x2 -> bf16x2 (RNE), 1 instr for 2 elements
__device__ __forceinline__ unsigned cvtpk(float lo, float hi) {
    unsigned r;
    asm("v_cvt_pk_bf16_f32 %0, %1, %2" : "=v"(r) : "v"(lo), "v"(hi));
    return r;
}
__device__ __forceinline__ void ij_of(int p, int& i, int& j) {
    float s = sqrtf(8.0f * (float)p + 1.0f);
    i = (int)((s - 1.0f) * 0.5f);
    while ((i + 1) * (i + 2) / 2 <= p) ++i;
    while (i * (i + 1) / 2 > p) --i;
    j = p - i * (i + 1) / 2;
}
// h1 chunk: relu(unpack(u)+unpack(v)) packed to 8 bf16 (one 16B chunk)
__device__ __forceinline__ uint4 build4(uint4 uu, uint4 vv) {
    unsigned ua[4] = {uu.x, uu.y, uu.z, uu.w};
    unsigned va[4] = {vv.x, vv.y, vv.z, vv.w};
    uint4 r;
    unsigned* rp = (unsigned*)&r;
    #pragma unroll
    for (int q = 0; q < 4; ++q) {
        float lo = asf(ua[q] << 16)         + asf(va[q] << 16);
        float hi = asf(ua[q] & 0xFFFF0000u) + asf(va[q] & 0xFFFF0000u);
        rp[q] = cvtpk(fmaxf(lo, 0.f), fmaxf(hi, 0.f));
    }
    return r;
}

// ---- fused preprocessing ------------------------------------------------
// grid (33, 8): x<32 -> U/V blocks; x==32 -> zero summed + transpose jobs
__global__ __launch_bounds__(256) void k_pre(
    const float* __restrict__ x, const float* __restrict__ code,
    const float* __restrict__ w1, const float* __restrict__ b1,
    const float* __restrict__ w2, const float* __restrict__ w3,
    unsigned short* __restrict__ ub, unsigned short* __restrict__ vb,
    unsigned short* __restrict__ w2t, unsigned short* __restrict__ w3t,
    float* __restrict__ summed)
{
    const int tid = threadIdx.x;
    if (blockIdx.x < 32) {
        const int ig = blockIdx.x, b = blockIdx.y, d = tid;
        float q = b1[d];
        const float* cp = code + b * 128;
        #pragma unroll 16
        for (int t = 0; t < 128; ++t) q += cp[t] * w1[(132 + t) * 256 + d];
        float su[8], sv[8];
        #pragma unroll
        for (int k = 0; k < 8; ++k) { su[k] = q; sv[k] = 0.f; }
        const float* xp = x + (b * 64) * 256 + ig * 8;
        #pragma unroll 8
        for (int c = 0; c < 64; ++c) {
            const float wu = w1[c * 256 + d];
            const float wv = w1[(66 + c) * 256 + d];
            const float* xc = xp + c * 256;          // uniform -> scalar loads
            #pragma unroll
            for (int k = 0; k < 8; ++k) { su[k] += xc[k] * wu; sv[k] += xc[k] * wv; }
        }
        const float wyu = w1[64 * 256 + d],  wxu = w1[65 * 256 + d];
        const float wyv = w1[130 * 256 + d], wxv = w1[131 * 256 + d];
        #pragma unroll
        for (int k = 0; k < 8; ++k) {
            const int i = ig * 8 + k;
            const float yy = (float)(i >> 4) * (2.0f / 15.0f) - 1.0f;
            const float xx = (float)(i & 15) * (2.0f / 15.0f) - 1.0f;
            ub[(b * 256 + i) * 256 + d] = f2bf(su[k] + yy * wyu + xx * wxu);
            vb[(b * 256 + i) * 256 + d] = f2bf(sv[k] + yy * wyv + xx * wxv);
        }
    } else {
        __shared__ float t[64][65];
        const int y = blockIdx.y;
        summed[y * 256 + tid] = 0.f;                 // re-zeroed every replay
        const int tx = tid & 63, ty = tid >> 6;
        for (int jj = 0; jj < 4; ++jj) {
            const int job = y * 4 + jj;              // 0..31
            const float* src = (job & 16) ? w3 : w2;
            unsigned short* dst = (job & 16) ? w3t : w2t;
            const int k0 = ((job >> 2) & 3) * 64, n0 = (job & 3) * 64;
            __syncthreads();
            #pragma unroll
            for (int r = ty; r < 64; r += 4) t[r][tx] = src[(k0 + r) * 256 + n0 + tx];
            __syncthreads();
            #pragma unroll
            for (int r = ty; r < 64; r += 4) dst[(n0 + r) * 256 + k0 + tx] = f2bf(t[tx][r]);
        }
    }
}

// ---- fused g_theta chain, 128 pairs per block ---------------------------
// Chunk swizzle: 16B chunk c of row r stored at chunk (c ^ (r&7)).
__global__ __launch_bounds__(512, 4) void k_fuse(
    const unsigned short* __restrict__ ub, const unsigned short* __restrict__ vb,
    const unsigned short* __restrict__ w2t, const unsigned short* __restrict__ w3t,
    const float* __restrict__ b2, const float* __restrict__ b3,
    float* __restrict__ summed)
{
    extern __shared__ unsigned short tile[];       // [128][256] bf16 = 64KiB
    const int tid  = threadIdx.x;
    const int pt   = blockIdx.x, b = blockIdx.y;
    const int lane = tid & 63, w = tid >> 6;       // wave w: n-cols w*32..+31
    const int lm   = lane & 15, quad = lane >> 4;

    // weight slice bases (lane lm -> n-row w*32+nt*16+lm, quad -> k group)
    const unsigned short* bb2 = w2t + ((w * 32 + lm) * 256) + quad * 8;
    const unsigned short* bb3 = w3t + ((w * 32 + lm) * 256) + quad * 8;

    // hoist GEMM1 W2 frags ks=0,1 (latency hidden under the h1 build)
    short8 bbuf[2][2];   // [parity][nt]
    #pragma unroll
    for (int kk = 0; kk < 2; ++kk)
        #pragma unroll
        for (int nt = 0; nt < 2; ++nt)
            bbuf[kk][nt] = *(const short8*)(bb2 + nt * 4096 + kk * 32);

    // ---- build h1 = relu(U_i + V_j) into LDS (each elem built once) ----
    {
        const int r = tid >> 2, qq = tid & 3;      // 4 threads/row, 64 k each
        const int p = pt * 128 + r;
        int i, j; ij_of(p, i, j);
        const unsigned short* up = ub + ((b * 256 + i) * 256) + qq * 64;
        const unsigned short* vp = vb + ((b * 256 + j) * 256) + qq * 64;
        const int rs = r & 7;
        #pragma unroll
        for (int it = 0; it < 8; ++it) {
            const uint4 uu = *(const uint4*)(up + it * 8);
            const uint4 vv = *(const uint4*)(vp + it * 8);
            const uint4 r4 = build4(uu, vv);
            const int chunk = qq * 8 + it;
            *(uint4*)(&tile[r * 256 + ((chunk ^ rs) << 3)]) = r4;
        }
    }
    __syncthreads();

    const float4v zero4 = {0.f, 0.f, 0.f, 0.f};

    // ---- GEMM1 (swapped, N-split): acc1[nt][mt] = h2^T slice;
    //      A = W2^T frag (L2, 2-deep prefetch), B = h1 frag (LDS) ----
    float4v acc1[2][8];
    #pragma unroll
    for (int nt = 0; nt < 2; ++nt)
        #pragma unroll
        for (int mt = 0; mt < 8; ++mt) acc1[nt][mt] = zero4;
    {
        for (int ks = 0; ks < 8; ++ks) {
            const int pr = ks & 1;
            short8 bcur[2];
            #pragma unroll
            for (int nt = 0; nt < 2; ++nt) bcur[nt] = bbuf[pr][nt];
            if (ks < 6) {
                #pragma unroll
                for (int nt = 0; nt < 2; ++nt)
                    bbuf[pr][nt] = *(const short8*)(bb2 + nt * 4096 + (ks + 2) * 32);
            }
            const int coff = ((ks * 4 + quad) ^ (lm & 7)) << 3;
            __builtin_amdgcn_s_setprio(1);
            #pragma unroll
            for (int half = 0; half < 2; ++half) {
                short8 afr[4];
                #pragma unroll
                for (int m = 0; m < 4; ++m)
                    afr[m] = *(const short8*)(
                        &tile[((half * 4 + m) * 16 + lm) * 256 + coff]);
                #pragma unroll
                for (int m = 0; m < 4; ++m)
                    #pragma unroll
                    for (int nt = 0; nt < 2; ++nt)
                        acc1[nt][half * 4 + m] = __builtin_amdgcn_mfma_f32_16x16x32_bf16(
                            bcur[nt], afr[m], acc1[nt][half * 4 + m], 0, 0, 0);
            }
            __builtin_amdgcn_s_setprio(0);
        }
    }
    __syncthreads();   // all h1 reads done; tile reusable

    // hoist GEMM2 W3 frags ks=0,1 (latency hidden under the scatter)
    #pragma unroll
    for (int kk = 0; kk < 2; ++kk)
        #pragma unroll
        for (int nt = 0; nt < 2; ++nt)
            bbuf[kk][nt] = *(const short8*)(bb3 + nt * 4096 + kk * 32);

    // ---- scatter h2 = relu(acc1+b2): acc is h2^T (lane lm = pair,
    //      n = w*32 + nt*16 + quad*4 + rg) -> 16 ds_write_b64/thread ----
    #pragma unroll
    for (int nt = 0; nt < 2; ++nt) {
        const float4 bbv = *(const float4*)(b2 + w * 32 + nt * 16 + quad * 4);
        #pragma unroll
        for (int mt = 0; mt < 8; ++mt) {
            const int row = mt * 16 + lm;              // pair
            const float v0 = fmaxf(acc1[nt][mt][0] + bbv.x, 0.f);
            const float v1 = fmaxf(acc1[nt][mt][1] + bbv.y, 0.f);
            const float v2 = fmaxf(acc1[nt][mt][2] + bbv.z, 0.f);
            const float v3 = fmaxf(acc1[nt][mt][3] + bbv.w, 0.f);
            uint2 pk; pk.x = cvtpk(v0, v1); pk.y = cvtpk(v2, v3);
            const int c0 = w * 4 + nt * 2 + (quad >> 1);   // 16B chunk of n
            *(uint2*)(&tile[row * 256 +
                            (((c0 ^ (row & 7)) << 3) | ((quad & 1) << 2))]) = pk;
        }
    }
    __syncthreads();

    // ---- GEMM2: rel = h2 @ W3, N-split (wave owns cols w*32..+31),
    //      A from LDS h2 tile, B = W3^T slice from L2 (2-deep prefetch) ----
    float4v acc2[8][2];
    #pragma unroll
    for (int mt = 0; mt < 8; ++mt)
        #pragma unroll
        for (int nt = 0; nt < 2; ++nt) acc2[mt][nt] = zero4;
    {
        for (int ks = 0; ks < 8; ++ks) {
            const int pr = ks & 1;
            short8 bcur[2];
            #pragma unroll
            for (int nt = 0; nt < 2; ++nt) bcur[nt] = bbuf[pr][nt];
            if (ks < 6) {
                #pragma unroll
                for (int nt = 0; nt < 2; ++nt)
                    bbuf[pr][nt] = *(const short8*)(bb3 + nt * 4096 + (ks + 2) * 32);
            }
            const int coff = ((ks * 4 + quad) ^ (lm & 7)) << 3;
            __builtin_amdgcn_s_setprio(1);
            #pragma unroll
            for (int mt = 0; mt < 8; ++mt) {
                const short8 a = *(const short8*)(
                    &tile[(mt * 16 + lm) * 256 + coff]);
                #pragma unroll
                for (int nt = 0; nt < 2; ++nt)
                    acc2[mt][nt] = __builtin_amdgcn_mfma_f32_16x16x32_bf16(
                        a, bcur[nt], acc2[mt][nt], 0, 0, 0);
            }
            __builtin_amdgcn_s_setprio(0);
        }
    }

    // ---- relu + column-sum over 128 pairs -> atomicAdd summed[b][col] ----
    #pragma unroll
    for (int nt = 0; nt < 2; ++nt) {
        const int col = w * 32 + nt * 16 + lm;
        const float bb = b3[col];
        float s = 0.f;
        #pragma unroll
        for (int mt = 0; mt < 8; ++mt)
            #pragma unroll
            for (int rg = 0; rg < 4; ++rg)
                s += fmaxf(acc2[mt][nt][rg] + bb, 0.f);
        s += __shfl_xor(s, 16);
        s += __shfl_xor(s, 32);
        if (quad == 0)
            atomicAdd(&summed[b * 256 + col], s);
    }
}

// ---- f_phi (fp32), 1024 threads: 4-way k-split per 256-wide layer -------
__global__ __launch_bounds__(1024) void k_tail(
    const float* __restrict__ summed,
    const float* __restrict__ fw1, const float* __restrict__ fb1,
    const float* __restrict__ fw2, const float* __restrict__ fb2,
    const float* __restrict__ fw3, const float* __restrict__ fb3,
    float* __restrict__ out)
{
    __shared__ float s0[256], s1[256], red[1024];
    const int b = blockIdx.x, tid = threadIdx.x;
    const int d = tid & 255, kh = tid >> 8;     // kh 0..3
    if (tid < 256) s0[tid] = summed[b * 256 + tid];
    __syncthreads();
    float p = 0.f;
    #pragma unroll 16
    for (int k = kh * 64; k < kh * 64 + 64; ++k) p += s0[k] * fw1[k * 256 + d];
    red[kh * 256 + d] = p;
    __syncthreads();
    if (tid < 256)
        s1[tid] = fmaxf(red[tid] + red[256 + tid] + red[512 + tid] + red[768 + tid]
                        + fb1[tid], 0.f);
    __syncthreads();
    p = 0.f;
    #pragma unroll 16
    for (int k = kh * 64; k < kh * 64 + 64; ++k) p += s1[k] * fw2[k * 256 + d];
    red[kh * 256 + d] = p;
    __syncthreads();
    if (tid < 256)
        s0[tid] = fmaxf(red[tid] + red[256 + tid] + red[512 + tid] + red[768 + tid]
                        + fb2[tid], 0.f);
    __syncthreads();
    const int d3 = tid & 31, kh3 = tid >> 5;    // kh3 0..31
    p = 0.f;
    #pragma unroll
    for (int k = kh3 * 8; k < kh3 * 8 + 8; ++k) p += s0[k] * fw3[k * 32 + d3];
    red[kh3 * 32 + d3] = p;
    __syncthreads();
    if (tid < 32) {
        float o = fb3[tid];
        #pragma unroll 8
        for (int r = 0; r < 32; ++r) o += red[r * 32 + tid];
        out[b * 32 + tid] = o;
    }
}

extern "C" void kernel_launch(void* const* d_in, const int* in_sizes, int n_in,
                              void* d_out, int out_size, void* d_ws, size_t ws_size,
                              hipStream_t stream) {
    const float* x    = (const float*)d_in[0];
    const float* code = (const float*)d_in[1];
    const float* gw1  = (const float*)d_in[2];
    const float* gb1  = (const float*)d_in[3];
    const float* gw2  = (const float*)d_in[4];
    const float* gb2  = (const float*)d_in[5];
    const float* gw3  = (const float*)d_in[6];
    const float* gb3  = (const float*)d_in[7];
    const float* fw1  = (const float*)d_in[8];
    const float* fb1  = (const float*)d_in[9];
    const float* fw2  = (const float*)d_in[10];
    const float* fb2  = (const float*)d_in[11];
    const float* fw3  = (const float*)d_in[12];
    const float* fb3  = (const float*)d_in[13];
    float* out = (float*)d_out;

    // workspace layout (bytes), total ~2.27 MB
    char* ws = (char*)d_ws;
    unsigned short* ub  = (unsigned short*)(ws);               // 1 MiB
    unsigned short* vb  = (unsigned short*)(ws + 1048576);     // 1 MiB
    unsigned short* w2t = (unsigned short*)(ws + 2097152);     // 128 KiB
    unsigned short* w3t = (unsigned short*)(ws + 2228224);     // 128 KiB
    float* summed = (float*)(ws + 2359296);                    // 8 KiB

    hipLaunchKernelGGL(k_pre, dim3(33, 8), dim3(256), 0, stream,
                       x, code, gw1, gb1, gw2, gw3, ub, vb, w2t, w3t, summed);
    hipLaunchKernelGGL(k_fuse, dim3(NTILE, 8), dim3(512), 65536, stream,
                       ub, vb, w2t, w3t, gb2, gb3, summed);
    hipLaunchKernelGGL(k_tail, dim3(8), dim3(1024), 0, stream,
                       summed, fw1, fb1, fw2, fb2, fw3, fb3, out);
}

// Round 11
// 187.672 us; speedup vs baseline: 1.1216x; 1.1216x over previous
//
#include <hip/hip_runtime.h>
#include <stdint.h>

// RelationalNetwork: B=8, C=64, O=256, TE=128, GT=FP=256, A=32
// v11 = v9 hot loop + grid quantization fix:
//   k_pre : W2/W3 transpose->bf16, summed:=0, U/V precompute (pipelined)
//   k_fuse: grid (128,8) = 1024 UNIFORM blocks (exactly 4 rounds of 256 CUs),
//           256 full pairs each, no masking. W2^T staged in LDS once; GEMM1
//           M-split swapped mfma(W2,h1) with in-reg h1 (3-deep U/V prefetch),
//           b64 h2^T scatter; GEMM2 N-split with W3^T from L2 (2-deep);
//           colsum -> atomicAdd summed.
//   k_tail: 8 blocks x 1024 thr; first computes the leftover 128 pairs of
//           its batch (same proven pattern, waves 0-7), adds into summed[b]
//           locally, then f_phi.

#define NPAIR 32896   // 256*257/2; k_fuse covers 32768, k_tail the last 128

using short8  = __attribute__((ext_vector_type(8))) short;
using float4v = __attribute__((ext_vector_type(4))) float;

__device__ __forceinline__ float asf(unsigned u) {
    union { unsigned u; float f; } c; c.u = u; return c.f;
}
__device__ __forceinline__ unsigned short f2bf(float f) {
    union { float f; unsigned u; } c; c.f = f;
    unsigned u = c.u;
    u += 0x7FFFu + ((u >> 16) & 1u);   // RNE
    return (unsigned short)(u >> 16);
}
// packed f32x2 -> bf16x2 (RNE), 1 instr for 2 elements
__device__ __forceinline__ unsigned cvtpk(float lo, float hi) {
    unsigned r;
    asm("v_cvt_pk_bf16_f32 %0, %1, %2" : "=v"(r) : "v"(lo), "v"(hi));
    return r;
}
__device__ __forceinline__ void ij_of(int p, int& i, int& j) {
    float s = sqrtf(8.0f * (float)p + 1.0f);
    i = (int)((s - 1.0f) * 0.5f);
    while ((i + 1) * (i + 2) / 2 <= p) ++i;
    while (i * (i + 1) / 2 > p) --i;
    j = p - i * (i + 1) / 2;
}
// h1 A-fragment: relu(unpack(u)+unpack(v)) packed to 8 bf16
__device__ __forceinline__ short8 buildA(uint4 uu, uint4 vv) {
    unsigned ua[4] = {uu.x, uu.y, uu.z, uu.w};
    unsigned va[4] = {vv.x, vv.y, vv.z, vv.w};
    union { unsigned u[4]; short8 s; } c;
    #pragma unroll
    for (int q = 0; q < 4; ++q) {
        float lo = asf(ua[q] << 16)         + asf(va[q] << 16);
        float hi = asf(ua[q] & 0xFFFF0000u) + asf(va[q] & 0xFFFF0000u);
        c.u[q] = cvtpk(fmaxf(lo, 0.f), fmaxf(hi, 0.f));
    }
    return c.s;
}

// ---- fused preprocessing ------------------------------------------------
// grid (33, 8): x<32 -> U/V blocks; x==32 -> zero summed + transpose jobs
__global__ __launch_bounds__(256) void k_pre(
    const float* __restrict__ x, const float* __restrict__ code,
    const float* __restrict__ w1, const float* __restrict__ b1,
    const float* __restrict__ w2, const float* __restrict__ w3,
    unsigned short* __restrict__ ub, unsigned short* __restrict__ vb,
    unsigned short* __restrict__ w2t, unsigned short* __restrict__ w3t,
    float* __restrict__ summed)
{
    const int tid = threadIdx.x;
    if (blockIdx.x < 32) {
        const int ig = blockIdx.x, b = blockIdx.y, d = tid;
        float q = b1[d];
        const float* cp = code + b * 128;
        #pragma unroll 16
        for (int t = 0; t < 128; ++t) q += cp[t] * w1[(132 + t) * 256 + d];
        float su[8], sv[8];
        #pragma unroll
        for (int k = 0; k < 8; ++k) { su[k] = q; sv[k] = 0.f; }
        const float* xp = x + (b * 64) * 256 + ig * 8;
        #pragma unroll 8
        for (int c = 0; c < 64; ++c) {
            const float wu = w1[c * 256 + d];
            const float wv = w1[(66 + c) * 256 + d];
            const float* xc = xp + c * 256;          // uniform -> scalar loads
            #pragma unroll
            for (int k = 0; k < 8; ++k) { su[k] += xc[k] * wu; sv[k] += xc[k] * wv; }
        }
        const float wyu = w1[64 * 256 + d],  wxu = w1[65 * 256 + d];
        const float wyv = w1[130 * 256 + d], wxv = w1[131 * 256 + d];
        #pragma unroll
        for (int k = 0; k < 8; ++k) {
            const int i = ig * 8 + k;
            const float yy = (float)(i >> 4) * (2.0f / 15.0f) - 1.0f;
            const float xx = (float)(i & 15) * (2.0f / 15.0f) - 1.0f;
            ub[(b * 256 + i) * 256 + d] = f2bf(su[k] + yy * wyu + xx * wxu);
            vb[(b * 256 + i) * 256 + d] = f2bf(sv[k] + yy * wyv + xx * wxv);
        }
    } else {
        __shared__ float t[64][65];
        const int y = blockIdx.y;
        summed[y * 256 + tid] = 0.f;                 // re-zeroed every replay
        const int tx = tid & 63, ty = tid >> 6;
        for (int jj = 0; jj < 4; ++jj) {
            const int job = y * 4 + jj;              // 0..31
            const float* src = (job & 16) ? w3 : w2;
            unsigned short* dst = (job & 16) ? w3t : w2t;
            const int k0 = ((job >> 2) & 3) * 64, n0 = (job & 3) * 64;
            __syncthreads();
            #pragma unroll
            for (int r = ty; r < 64; r += 4) t[r][tx] = src[(k0 + r) * 256 + n0 + tx];
            __syncthreads();
            #pragma unroll
            for (int r = ty; r < 64; r += 4) dst[(n0 + r) * 256 + k0 + tx] = f2bf(t[tx][r]);
        }
    }
}

// ---- fused g_theta chain for 256 pairs (uniform full tiles) -------------
// Chunk swizzle everywhere: 16B chunk c of row r stored at chunk (c ^ (r&7)).
__global__ __launch_bounds__(512) void k_fuse(
    const unsigned short* __restrict__ ub, const unsigned short* __restrict__ vb,
    const unsigned short* __restrict__ w2t, const unsigned short* __restrict__ w3t,
    const float* __restrict__ b2, const float* __restrict__ b3,
    float* __restrict__ summed)
{
    extern __shared__ unsigned short lds[];        // 128 KiB
    const int tid  = threadIdx.x;
    const int pt   = blockIdx.x, b = blockIdx.y;
    const int lane = tid & 63, w = tid >> 6;
    const int lm   = lane & 15, quad = lane >> 4;

    // ---- stage W2^T[n][k] into LDS, chunk-swizzled ----
    #pragma unroll
    for (int it = 0; it < 16; ++it) {
        const int idx = it * 512 + tid;
        const int n = idx >> 5, c = idx & 31;
        const uint4 d = *(const uint4*)(w2t + n * 256 + c * 8);
        *(uint4*)(&lds[n * 256 + ((c ^ (n & 7)) << 3)]) = d;
    }

    // ---- GEMM1 row setup (wave owns rows w*32..w*32+31; always valid) ----
    const unsigned short* up[2];
    const unsigned short* vp[2];
    #pragma unroll
    for (int mt = 0; mt < 2; ++mt) {
        const int p = pt * 256 + w * 32 + mt * 16 + lm;   // < 32768 always
        int i, j; ij_of(p, i, j);
        up[mt] = ub + ((b * 256 + i) * 256) + quad * 8;
        vp[mt] = vb + ((b * 256 + j) * 256) + quad * 8;
    }
    __syncthreads();

    const float4v zero4 = {0.f, 0.f, 0.f, 0.f};

    // ---- GEMM1 (SWAPPED): acc1[nt][mt] = h2^T; A = W2frag (LDS),
    //      B = h1frag built in-reg from U/V (3-deep prefetch) ----
    float4v acc1[16][2];
    #pragma unroll
    for (int nt = 0; nt < 16; ++nt)
        #pragma unroll
        for (int mt = 0; mt < 2; ++mt) acc1[nt][mt] = zero4;
    {
        uint4 cu[3][2], cv[3][2];    // [slot][mt]
        #pragma unroll
        for (int kk = 0; kk < 3; ++kk)
            #pragma unroll
            for (int mt = 0; mt < 2; ++mt) {
                cu[kk][mt] = *(const uint4*)(up[mt] + kk * 32);
                cv[kk][mt] = *(const uint4*)(vp[mt] + kk * 32);
            }
        #pragma unroll
        for (int ks = 0; ks < 8; ++ks) {
            const int pr = ks % 3;
            short8 afr[2];
            #pragma unroll
            for (int mt = 0; mt < 2; ++mt) afr[mt] = buildA(cu[pr][mt], cv[pr][mt]);
            if (ks < 5) {
                #pragma unroll
                for (int mt = 0; mt < 2; ++mt) {
                    cu[pr][mt] = *(const uint4*)(up[mt] + (ks + 3) * 32);
                    cv[pr][mt] = *(const uint4*)(vp[mt] + (ks + 3) * 32);
                }
            }
            const int coff = ((ks * 4 + quad) ^ (lm & 7)) << 3;
            __builtin_amdgcn_s_setprio(1);
            #pragma unroll
            for (int ng = 0; ng < 4; ++ng) {
                short8 bfr[4];
                #pragma unroll
                for (int q = 0; q < 4; ++q)
                    bfr[q] = *(const short8*)(&lds[((ng * 4 + q) * 16 + lm) * 256 + coff]);
                #pragma unroll
                for (int q = 0; q < 4; ++q)
                    #pragma unroll
                    for (int mt = 0; mt < 2; ++mt)
                        acc1[ng * 4 + q][mt] = __builtin_amdgcn_mfma_f32_16x16x32_bf16(
                            bfr[q], afr[mt], acc1[ng * 4 + q][mt], 0, 0, 0);
            }
            __builtin_amdgcn_s_setprio(0);
        }
    }
    __syncthreads();   // all waves done reading W2 region

    // ---- hoist GEMM2 B-frags ks=0,1 (latency hidden under the scatter) --
    const unsigned short* bb3 = w3t + ((w * 32 + lm) * 256) + quad * 8;
    short8 bbuf[2][2];   // [parity][nt]
    #pragma unroll
    for (int kk = 0; kk < 2; ++kk)
        #pragma unroll
        for (int nt = 0; nt < 2; ++nt)
            bbuf[kk][nt] = *(const short8*)(bb3 + nt * 4096 + kk * 32);

    // ---- scatter h2 = relu(acc1+b2): acc is h2^T (lane lm = pair,
    //      n = nt*16 + quad*4 + rg) -> 32 ds_write_b64/thread ----
    #pragma unroll
    for (int nt = 0; nt < 16; ++nt) {
        const float4 bbv = *(const float4*)(b2 + nt * 16 + quad * 4);
        #pragma unroll
        for (int mt = 0; mt < 2; ++mt) {
            const int row = w * 32 + mt * 16 + lm;     // pair
            const float v0 = fmaxf(acc1[nt][mt][0] + bbv.x, 0.f);
            const float v1 = fmaxf(acc1[nt][mt][1] + bbv.y, 0.f);
            const float v2 = fmaxf(acc1[nt][mt][2] + bbv.z, 0.f);
            const float v3 = fmaxf(acc1[nt][mt][3] + bbv.w, 0.f);
            uint2 pk; pk.x = cvtpk(v0, v1); pk.y = cvtpk(v2, v3);
            const int c0 = nt * 2 + (quad >> 1);       // 16B chunk of n
            *(uint2*)(&lds[row * 256 + (((c0 ^ (row & 7)) << 3) | ((quad & 1) << 2))]) = pk;
        }
    }
    __syncthreads();

    // ---- GEMM2: rel = h2 @ W3, N-split (wave owns cols w*32..+31),
    //      A from LDS h2 tile, B = W3^T slice from L2 (2-deep prefetch) ----
    float4v acc2[16][2];
    #pragma unroll
    for (int mt = 0; mt < 16; ++mt)
        #pragma unroll
        for (int nt = 0; nt < 2; ++nt) acc2[mt][nt] = zero4;
    {
        for (int ks = 0; ks < 8; ++ks) {
            const int pr = ks & 1;
            short8 bcur[2];
            #pragma unroll
            for (int nt = 0; nt < 2; ++nt) bcur[nt] = bbuf[pr][nt];
            if (ks < 6) {
                #pragma unroll
                for (int nt = 0; nt < 2; ++nt)
                    bbuf[pr][nt] = *(const short8*)(bb3 + nt * 4096 + (ks + 2) * 32);
            }
            __builtin_amdgcn_s_setprio(1);
            #pragma unroll
            for (int mt = 0; mt < 16; ++mt) {
                const int row = mt * 16 + lm;
                const short8 a = *(const short8*)(
                    &lds[row * 256 + (((ks * 4 + quad) ^ (row & 7)) << 3)]);
                #pragma unroll
                for (int nt = 0; nt < 2; ++nt)
                    acc2[mt][nt] = __builtin_amdgcn_mfma_f32_16x16x32_bf16(
                        a, bcur[nt], acc2[mt][nt], 0, 0, 0);
            }
            __builtin_amdgcn_s_setprio(0);
        }
    }

    // ---- relu + column-sum over all 256 rows -> atomicAdd summed[b][col] ----
    #pragma unroll
    for (int nt = 0; nt < 2; ++nt) {
        const int col = w * 32 + nt * 16 + lm;
        const float bb = b3[col];
        float s = 0.f;
        #pragma unroll
        for (int mt = 0; mt < 16; ++mt)
            #pragma unroll
            for (int rg = 0; rg < 4; ++rg)
                s += fmaxf(acc2[mt][nt][rg] + bb, 0.f);
        s += __shfl_xor(s, 16);
        s += __shfl_xor(s, 32);
        if (quad == 0)
            atomicAdd(&summed[b * 256 + col], s);
    }
}

// ---- leftover 128 pairs (g_theta) + f_phi -------------------------------
// 8 blocks (one per b) x 1024 threads; waves 0-7 run the GEMM chain for
// pairs 32768..32895, add into summed[b] locally, then all run f_phi.
__global__ __launch_bounds__(1024) void k_tail(
    const unsigned short* __restrict__ ub, const unsigned short* __restrict__ vb,
    const unsigned short* __restrict__ w2t, const unsigned short* __restrict__ w3t,
    const float* __restrict__ b2, const float* __restrict__ b3,
    const float* __restrict__ summed,
    const float* __restrict__ fw1, const float* __restrict__ fb1,
    const float* __restrict__ fw2, const float* __restrict__ fb2,
    const float* __restrict__ fw3, const float* __restrict__ fb3,
    float* __restrict__ out)
{
    extern __shared__ unsigned short lds[];        // 128KiB tile + 7KiB f32
    float* ext = (float*)(lds + 65536);            // [256]
    float* s0  = ext + 256;                        // [256]
    float* s1  = s0 + 256;                         // [256]
    float* red = s1 + 256;                         // [1024]
    const int b = blockIdx.x, tid = threadIdx.x;
    const int lane = tid & 63, w = tid >> 6;
    const int lm = lane & 15, quad = lane >> 4;
    const float4v zero4 = {0.f, 0.f, 0.f, 0.f};

    // stage W2^T swizzled (all 1024 threads)
    #pragma unroll
    for (int it = 0; it < 8; ++it) {
        const int idx = it * 1024 + tid;
        const int n = idx >> 5, c = idx & 31;
        const uint4 d4 = *(const uint4*)(w2t + n * 256 + c * 8);
        *(uint4*)(&lds[n * 256 + ((c ^ (n & 7)) << 3)]) = d4;
    }
    // pair setup (waves 0-7 own 16 pairs each; clamp for idle waves)
    const int pp = 32768 + w * 16 + lm;
    const int p  = pp < NPAIR ? pp : NPAIR - 1;
    int i, j; ij_of(p, i, j);
    const unsigned short* up = ub + ((b * 256 + i) * 256) + quad * 8;
    const unsigned short* vp = vb + ((b * 256 + j) * 256) + quad * 8;
    __syncthreads();

    // GEMM1 (swapped): acc1[nt] = h2^T for this wave's 16 pairs
    float4v acc1[16];
    #pragma unroll
    for (int nt = 0; nt < 16; ++nt) acc1[nt] = zero4;
    if (tid < 512) {
        #pragma unroll
        for (int ks = 0; ks < 8; ++ks) {
            const uint4 cu = *(const uint4*)(up + ks * 32);
            const uint4 cv = *(const uint4*)(vp + ks * 32);
            const short8 afr = buildA(cu, cv);
            const int coff = ((ks * 4 + quad) ^ (lm & 7)) << 3;
            #pragma unroll
            for (int nt = 0; nt < 16; ++nt) {
                const short8 bfr = *(const short8*)(&lds[(nt * 16 + lm) * 256 + coff]);
                acc1[nt] = __builtin_amdgcn_mfma_f32_16x16x32_bf16(
                    bfr, afr, acc1[nt], 0, 0, 0);
            }
        }
    }
    __syncthreads();   // GEMM1 LDS reads done; tile reusable

    if (tid < 512) {   // scatter h2 rows 0..127 (swizzled, same encoding)
        #pragma unroll
        for (int nt = 0; nt < 16; ++nt) {
            const float4 bbv = *(const float4*)(b2 + nt * 16 + quad * 4);
            const int row = w * 16 + lm;               // pair row 0..127
            const float v0 = fmaxf(acc1[nt][0] + bbv.x, 0.f);
            const float v1 = fmaxf(acc1[nt][1] + bbv.y, 0.f);
            const float v2 = fmaxf(acc1[nt][2] + bbv.z, 0.f);
            const float v3 = fmaxf(acc1[nt][3] + bbv.w, 0.f);
            uint2 pk; pk.x = cvtpk(v0, v1); pk.y = cvtpk(v2, v3);
            const int c0 = nt * 2 + (quad >> 1);
            *(uint2*)(&lds[row * 256 + (((c0 ^ (row & 7)) << 3) | ((quad & 1) << 2))]) = pk;
        }
    }
    __syncthreads();

    // GEMM2: N-split, wave w cols w*32..+31, rows 0..127
    float4v acc2[8][2];
    #pragma unroll
    for (int mt = 0; mt < 8; ++mt)
        #pragma unroll
        for (int nt = 0; nt < 2; ++nt) acc2[mt][nt] = zero4;
    if (tid < 512) {
        const unsigned short* bb3 = w3t + ((w * 32 + lm) * 256) + quad * 8;
        #pragma unroll
        for (int ks = 0; ks < 8; ++ks) {
            short8 bcur[2];
            #pragma unroll
            for (int nt = 0; nt < 2; ++nt)
                bcur[nt] = *(const short8*)(bb3 + nt * 4096 + ks * 32);
            const int coff = ((ks * 4 + quad) ^ (lm & 7)) << 3;
            #pragma unroll
            for (int mt = 0; mt < 8; ++mt) {
                const int row = mt * 16 + lm;
                const short8 a = *(const short8*)(
                    &lds[row * 256 + (((ks * 4 + quad) ^ (row & 7)) << 3)]);
                #pragma unroll
                for (int nt = 0; nt < 2; ++nt)
                    acc2[mt][nt] = __builtin_amdgcn_mfma_f32_16x16x32_bf16(
                        a, bcur[nt], acc2[mt][nt], 0, 0, 0);
            }
        }
        #pragma unroll
        for (int nt = 0; nt < 2; ++nt) {
            const int col = w * 32 + nt * 16 + lm;
            const float bb = b3[col];
            float s = 0.f;
            #pragma unroll
            for (int mt = 0; mt < 8; ++mt)
                #pragma unroll
                for (int rg = 0; rg < 4; ++rg)
                    s += fmaxf(acc2[mt][nt][rg] + bb, 0.f);
            s += __shfl_xor(s, 16);
            s += __shfl_xor(s, 32);
            if (quad == 0) ext[col] = s;
        }
    }
    __syncthreads();

    // ---- f_phi (fp32), 4-way k-split per 256-wide layer ----
    const int d = tid & 255, kh = tid >> 8;     // kh 0..3
    if (tid < 256) s0[tid] = summed[b * 256 + tid] + ext[tid];
    __syncthreads();
    float pk = 0.f;
    #pragma unroll 16
    for (int k = kh * 64; k < kh * 64 + 64; ++k) pk += s0[k] * fw1[k * 256 + d];
    red[kh * 256 + d] = pk;
    __syncthreads();
    if (tid < 256)
        s1[tid] = fmaxf(red[tid] + red[256 + tid] + red[512 + tid] + red[768 + tid]
                        + fb1[tid], 0.f);
    __syncthreads();
    pk = 0.f;
    #pragma unroll 16
    for (int k = kh * 64; k < kh * 64 + 64; ++k) pk += s1[k] * fw2[k * 256 + d];
    red[kh * 256 + d] = pk;
    __syncthreads();
    if (tid < 256)
        s0[tid] = fmaxf(red[tid] + red[256 + tid] + red[512 + tid] + red[768 + tid]
                        + fb2[tid], 0.f);
    __syncthreads();
    const int d3 = tid & 31, kh3 = tid >> 5;    // kh3 0..31
    pk = 0.f;
    #pragma unroll
    for (int k = kh3 * 8; k < kh3 * 8 + 8; ++k) pk += s0[k] * fw3[k * 32 + d3];
    red[kh3 * 32 + d3] = pk;
    __syncthreads();
    if (tid < 32) {
        float o = fb3[tid];
        #pragma unroll 8
        for (int r = 0; r < 32; ++r) o += red[r * 32 + tid];
        out[b * 32 + tid] = o;
    }
}

extern "C" void kernel_launch(void* const* d_in, const int* in_sizes, int n_in,
                              void* d_out, int out_size, void* d_ws, size_t ws_size,
                              hipStream_t stream) {
    const float* x    = (const float*)d_in[0];
    const float* code = (const float*)d_in[1];
    const float* gw1  = (const float*)d_in[2];
    const float* gb1  = (const float*)d_in[3];
    const float* gw2  = (const float*)d_in[4];
    const float* gb2  = (const float*)d_in[5];
    const float* gw3  = (const float*)d_in[6];
    const float* gb3  = (const float*)d_in[7];
    const float* fw1  = (const float*)d_in[8];
    const float* fb1  = (const float*)d_in[9];
    const float* fw2  = (const float*)d_in[10];
    const float* fb2  = (const float*)d_in[11];
    const float* fw3  = (const float*)d_in[12];
    const float* fb3  = (const float*)d_in[13];
    float* out = (float*)d_out;

    // workspace layout (bytes), total ~2.27 MB
    char* ws = (char*)d_ws;
    unsigned short* ub  = (unsigned short*)(ws);               // 1 MiB
    unsigned short* vb  = (unsigned short*)(ws + 1048576);     // 1 MiB
    unsigned short* w2t = (unsigned short*)(ws + 2097152);     // 128 KiB
    unsigned short* w3t = (unsigned short*)(ws + 2228224);     // 128 KiB
    float* summed = (float*)(ws + 2359296);                    // 8 KiB

    hipLaunchKernelGGL(k_pre, dim3(33, 8), dim3(256), 0, stream,
                       x, code, gw1, gb1, gw2, gw3, ub, vb, w2t, w3t, summed);
    hipLaunchKernelGGL(k_fuse, dim3(128, 8), dim3(512), 131072, stream,
                       ub, vb, w2t, w3t, gb2, gb3, summed);
    hipLaunchKernelGGL(k_tail, dim3(8), dim3(1024), 138240, stream,
                       ub, vb, w2t, w3t, gb2, gb3, summed,
                       fw1, fb1, fw2, fb2, fw3, fb3, out);
}